// Round 4
// baseline (342.299 us; speedup 1.0000x reference)
//
#include <hip/hip_runtime.h>
#include <hip/hip_bf16.h>
#include <math.h>

#define BB 256
#define NN 5
#define DD 2048
#define CC 1000
#define HH 1024
#define PROTO_M 0.999f

typedef unsigned short u16;
typedef __attribute__((ext_vector_type(8))) short short8;   // 8 bf16
typedef __attribute__((ext_vector_type(4))) float f32x4;

__device__ __forceinline__ u16 f2bf(float f) {
    union { float f; unsigned u; } x; x.f = f;
    unsigned r = x.u + 0x7fff + ((x.u >> 16) & 1);   // RNE
    return (u16)(r >> 16);
}
__device__ __forceinline__ float bf2f(u16 b) {
    union { unsigned u; float f; } x; x.u = ((unsigned)b) << 16;
    return x.f;
}

// async global->LDS, 16B per lane; lds dest = wave-uniform base + lane*16
__device__ __forceinline__ void gload16(const u16* g, u16* l) {
    __builtin_amdgcn_global_load_lds(
        (const __attribute__((address_space(1))) unsigned int*)g,
        (__attribute__((address_space(3))) unsigned int*)l, 16, 0, 0);
}

// ---------------------------------------------------------------------------
// Transpose + f32->bf16: in f32 [K][N] -> out bf16 [N][K]. 64x64 tile.
// OOB n-rows are written as ZEROS (gload_lds B staging reads padded rows).
// ---------------------------------------------------------------------------
__global__ __launch_bounds__(256) void transpose_bf16(const float* __restrict__ in,
                                                      u16* __restrict__ out,
                                                      int K, int N) {
    constexpr int STR = 72;
    __shared__ u16 T[64 * STR];
    const int k0 = blockIdx.x * 64, n0 = blockIdx.y * 64;
    const int t = threadIdx.x;
    const int c4 = t % 16;
    const int rr = t / 16;
#pragma unroll
    for (int p = 0; p < 4; ++p) {
        int k = p * 16 + rr;
        int n = c4 * 4;
        if (n0 + n < N) {
            float4 v = *(const float4*)(in + (size_t)(k0 + k) * N + n0 + n);
            T[(n + 0) * STR + k] = f2bf(v.x);
            T[(n + 1) * STR + k] = f2bf(v.y);
            T[(n + 2) * STR + k] = f2bf(v.z);
            T[(n + 3) * STR + k] = f2bf(v.w);
        }
    }
    __syncthreads();
    const int ch = t % 8;
    const int nl0 = t / 8;
    const short8 zero8 = {0, 0, 0, 0, 0, 0, 0, 0};
#pragma unroll
    for (int q = 0; q < 2; ++q) {
        int nl = nl0 + q * 32;
        short8 v = zero8;
        if (n0 + nl < N) v = *(const short8*)(&T[nl * STR + ch * 8]);
        *(short8*)(out + (size_t)(n0 + nl) * K + k0 + ch * 8) = v;
    }
}

// ---------------------------------------------------------------------------
// adj mix: Y[b,n,d] = sum_m adj[n,m] * relu?(X[b,m,d]), bf16 out, float4-wide.
// ---------------------------------------------------------------------------
template<bool IN_BF16, bool RELU_IN>
__global__ __launch_bounds__(256) void adj_mix(const float* __restrict__ adjp,
                                               const void* __restrict__ X,
                                               u16* __restrict__ Y, int Dd) {
    __shared__ float as_[NN * NN];
    if (threadIdx.x < NN * NN) as_[threadIdx.x] = adjp[threadIdx.x];
    __syncthreads();
    const int d4n = Dd / 4;
    int idx = blockIdx.x * blockDim.x + threadIdx.x;   // exact grid
    int b = idx / d4n, d4 = idx % d4n;
    float xv[NN][4];
#pragma unroll
    for (int m = 0; m < NN; ++m) {
        size_t base = ((size_t)b * NN + m) * Dd + d4 * 4;
        if (IN_BF16) {
            const ushort4 u = *(const ushort4*)((const u16*)X + base);
            xv[m][0] = bf2f(u.x); xv[m][1] = bf2f(u.y);
            xv[m][2] = bf2f(u.z); xv[m][3] = bf2f(u.w);
        } else {
            const float4 f = *(const float4*)((const float*)X + base);
            xv[m][0] = f.x; xv[m][1] = f.y; xv[m][2] = f.z; xv[m][3] = f.w;
        }
        if (RELU_IN) {
#pragma unroll
            for (int j = 0; j < 4; ++j) xv[m][j] = fmaxf(xv[m][j], 0.f);
        }
    }
#pragma unroll
    for (int n = 0; n < NN; ++n) {
        float s[4] = {0.f, 0.f, 0.f, 0.f};
#pragma unroll
        for (int m = 0; m < NN; ++m) {
            float a = as_[n * NN + m];
#pragma unroll
            for (int j = 0; j < 4; ++j) s[j] += a * xv[m][j];
        }
        ushort4 o;
        o.x = f2bf(s[0]); o.y = f2bf(s[1]); o.z = f2bf(s[2]); o.w = f2bf(s[3]);
        *(ushort4*)(Y + ((size_t)b * NN + n) * Dd + d4 * 4) = o;
    }
}

// ---------------------------------------------------------------------------
// bf16 MFMA GEMM, global_load_lds staging (m97 pattern):
//   per K-step(64): barrier; issue gload_lds (linear LDS dest, chunk-swizzled
//   global src, c^=row&7); barrier (vmcnt0 drain); swizzled ds_read_b128
//   fragments; MFMA. C = A[M,K] @ Bt[N,K]^T. 4 waves (2x2).
// Requires: M%BM==0, Bt rows allocated/zero-padded to n0+BN, Ks%64==0.
// ATOMIC: f32 atomicAdd epilogue (split-K). else bf16 store (+RELU opt).
// ---------------------------------------------------------------------------
template<int BM, int BN, bool ATOMIC, bool RELU>
__global__ __launch_bounds__(256) void gemm_gl(const u16* __restrict__ A,
                                               const u16* __restrict__ Bt,
                                               void* __restrict__ C,
                                               int M, int N, int K, int Ks) {
    constexpr int FM = BM / 32;
    constexpr int FN = BN / 32;
    constexpr int SEGA = BM / 32;   // gload issues per wave for A (BM/8 segs /4)
    constexpr int SEGB = BN / 32;
    __shared__ u16 As[BM * 64];
    __shared__ u16 Bs[BN * 64];
    const int t = threadIdx.x;
    const int lane = t & 63;
    const int w = t >> 6;
    const int wr = w >> 1, wc = w & 1;
    const int lr = lane & 15;
    const int kc = lane >> 4;
    const int lrow8 = lane >> 3;   // 0..7
    const int lc = lane & 7;       // chunk slot 0..7
    const int m0 = blockIdx.y * BM;
    const int n0 = blockIdx.x * BN;
    const int kz0 = blockIdx.z * Ks;

    f32x4 acc[FM][FN];
#pragma unroll
    for (int i = 0; i < FM; ++i)
#pragma unroll
        for (int j = 0; j < FN; ++j) acc[i][j] = (f32x4){0.f, 0.f, 0.f, 0.f};

    for (int k0 = kz0; k0 < kz0 + Ks; k0 += 64) {
        __syncthreads();   // prior ds_reads done before LDS overwrite
#pragma unroll
        for (int p = 0; p < SEGA; ++p) {
            int s = p * 4 + w;                    // 1KB segment
            int r = s * 8 + lrow8;                // tile row
            int cs = lc ^ (r & 7);                // inverse-swizzled source
            gload16(A + (size_t)(m0 + r) * K + k0 + cs * 8, &As[s * 512]);
        }
#pragma unroll
        for (int p = 0; p < SEGB; ++p) {
            int s = p * 4 + w;
            int r = s * 8 + lrow8;
            int cs = lc ^ (r & 7);
            gload16(Bt + (size_t)(n0 + r) * K + k0 + cs * 8, &Bs[s * 512]);
        }
        __syncthreads();   // vmcnt(0) drain + barrier: staging visible

#pragma unroll
        for (int ks = 0; ks < 2; ++ks) {
            short8 af[FM], bfr[FN];
#pragma unroll
            for (int i = 0; i < FM; ++i) {
                int row = wr * (BM / 2) + i * 16 + lr;
                int cs = (ks * 4 + kc) ^ (row & 7);
                af[i] = *(const short8*)(&As[row * 64 + cs * 8]);
            }
#pragma unroll
            for (int j = 0; j < FN; ++j) {
                int row = wc * (BN / 2) + j * 16 + lr;
                int cs = (ks * 4 + kc) ^ (row & 7);
                bfr[j] = *(const short8*)(&Bs[row * 64 + cs * 8]);
            }
#pragma unroll
            for (int i = 0; i < FM; ++i)
#pragma unroll
                for (int j = 0; j < FN; ++j)
                    acc[i][j] = __builtin_amdgcn_mfma_f32_16x16x32_bf16(
                        af[i], bfr[j], acc[i][j], 0, 0, 0);
        }
    }

    // epilogue: C/D layout col=lane&15, row=(lane>>4)*4+q
#pragma unroll
    for (int i = 0; i < FM; ++i) {
        int row = m0 + wr * (BM / 2) + i * 16 + kc * 4;
#pragma unroll
        for (int j = 0; j < FN; ++j) {
            int col = n0 + wc * (BN / 2) + j * 16 + lr;
            if (col >= N) continue;
#pragma unroll
            for (int q = 0; q < 4; ++q) {
                float v = acc[i][j][q];
                if (ATOMIC) {
                    atomicAdd((float*)C + (size_t)(row + q) * N + col, v);
                } else {
                    if (RELU) v = fmaxf(v, 0.f);
                    ((u16*)C)[(size_t)(row + q) * N + col] = f2bf(v);
                }
            }
        }
    }
}

// g_bf16 = bf16(g_f32 + bg)
__global__ __launch_bounds__(256) void finalize_g(const float* __restrict__ gf,
                                                  const float* __restrict__ bg,
                                                  u16* __restrict__ gb) {
    int idx = blockIdx.x * blockDim.x + threadIdx.x;
    int n4 = idx % (DD / 4);
    float4 v = *(const float4*)(gf + (size_t)idx * 4);
    float4 b = *(const float4*)(bg + n4 * 4);
    ushort4 o;
    o.x = f2bf(v.x + b.x); o.y = f2bf(v.y + b.y);
    o.z = f2bf(v.z + b.z); o.w = f2bf(v.w + b.w);
    *(ushort4*)(gb + (size_t)idx * 4) = o;
}

// out_pred = pred_f32 + bc
__global__ __launch_bounds__(256) void finalize_pred(const float* __restrict__ pf,
                                                     const float* __restrict__ bc,
                                                     float* __restrict__ out) {
    int idx = blockIdx.x * blockDim.x + threadIdx.x;
    int n4 = idx % 250;
    float4 v = *(const float4*)(pf + (size_t)idx * 4);
    float4 b = *(const float4*)(bc + n4 * 4);
    float4 o; o.x = v.x + b.x; o.y = v.y + b.y; o.z = v.z + b.z; o.w = v.w + b.w;
    *(float4*)(out + (size_t)idx * 4) = o;
}

// ---------------------------------------------------------------------------
// Rank/scan for EMA closed form (one 1024-thread block)
// ---------------------------------------------------------------------------
__global__ __launch_bounds__(1024) void rank_build(const int* __restrict__ target,
                                                   int* __restrict__ cnt,
                                                   int* __restrict__ start,
                                                   int* __restrict__ order,
                                                   float* __restrict__ coef,
                                                   float* __restrict__ decayc) {
    __shared__ int stgt[BB];
    __shared__ int scnt[1024];
    __shared__ int sscan[1024];
    const int t = threadIdx.x;
    scnt[t] = 0;
    if (t < BB) stgt[t] = target[t];
    __syncthreads();
    int myc = -1, posc = 0;
    if (t < BB) {
        myc = stgt[t];
        for (int b2 = 0; b2 < t; ++b2) posc += (stgt[b2] == myc) ? 1 : 0;
        atomicAdd(&scnt[myc], 1);
    }
    __syncthreads();
    sscan[t] = scnt[t];
    __syncthreads();
    for (int off = 1; off < 1024; off <<= 1) {
        int add = (t >= off) ? sscan[t - off] : 0;
        __syncthreads();
        sscan[t] += add;
        __syncthreads();
    }
    if (t < CC) {
        cnt[t] = scnt[t];
        start[t] = sscan[t] - scnt[t];
        decayc[t] = powf(PROTO_M, (float)scnt[t]);
    }
    __syncthreads();
    if (t < BB) {
        int s = sscan[myc] - scnt[myc];
        order[s + posc] = t;
        coef[s + posc] = (1.0f - PROTO_M) * powf(PROTO_M, (float)(scnt[myc] - 1 - posc));
    }
}

// ---------------------------------------------------------------------------
// Fused prototype update: out[c] = normalize(protos[c]*decay[c] +
//   sum_j coef_j * x[order_j]) over node axis. Block = (c, half-of-D).
// ---------------------------------------------------------------------------
__global__ __launch_bounds__(256) void proto_fused(const float* __restrict__ protos,
                                                   const float* __restrict__ x,
                                                   const int* __restrict__ cnt,
                                                   const int* __restrict__ start,
                                                   const int* __restrict__ order,
                                                   const float* __restrict__ coef,
                                                   const float* __restrict__ decayc,
                                                   float* __restrict__ out) {
    const int c = blockIdx.x >> 1;
    const int d = ((blockIdx.x & 1) * 256 + threadIdx.x) * 4;
    const float dec = decayc[c];
    const int k = cnt[c];
    const int s = start[c];
    float4 v[NN];
#pragma unroll
    for (int n = 0; n < NN; ++n) {
        float4 p = *(const float4*)(protos + ((size_t)c * NN + n) * DD + d);
        v[n].x = p.x * dec; v[n].y = p.y * dec; v[n].z = p.z * dec; v[n].w = p.w * dec;
    }
    for (int j = 0; j < k; ++j) {
        int b = order[s + j];
        float cf = coef[s + j];
#pragma unroll
        for (int n = 0; n < NN; ++n) {
            float4 xv = *(const float4*)(x + ((size_t)b * NN + n) * DD + d);
            v[n].x += cf * xv.x; v[n].y += cf * xv.y;
            v[n].z += cf * xv.z; v[n].w += cf * xv.w;
        }
    }
    float ss[4] = {0.f, 0.f, 0.f, 0.f};
#pragma unroll
    for (int n = 0; n < NN; ++n) {
        ss[0] += v[n].x * v[n].x; ss[1] += v[n].y * v[n].y;
        ss[2] += v[n].z * v[n].z; ss[3] += v[n].w * v[n].w;
    }
    float inv[4];
#pragma unroll
    for (int j = 0; j < 4; ++j) inv[j] = 1.0f / fmaxf(sqrtf(ss[j]), 1e-12f);
#pragma unroll
    for (int n = 0; n < NN; ++n) {
        float4 o;
        o.x = v[n].x * inv[0]; o.y = v[n].y * inv[1];
        o.z = v[n].z * inv[2]; o.w = v[n].w * inv[3];
        *(float4*)(out + ((size_t)c * NN + n) * DD + d) = o;
    }
}

// ---------------------------------------------------------------------------
extern "C" void kernel_launch(void* const* d_in, const int* in_sizes, int n_in,
                              void* d_out, int out_size, void* d_ws, size_t ws_size,
                              hipStream_t stream) {
    const float* x          = (const float*)d_in[0];
    const int*   target     = (const int*)d_in[1];
    const float* prototypes = (const float*)d_in[2];
    const float* adj        = (const float*)d_in[3];
    const float* W1         = (const float*)d_in[4];
    const float* W2         = (const float*)d_in[5];
    const float* Wg         = (const float*)d_in[6];
    const float* bg         = (const float*)d_in[7];
    const float* Wc         = (const float*)d_in[8];
    const float* bc         = (const float*)d_in[9];

    float* out_pred   = (float*)d_out;                    // [256,1000]
    float* out_protos = (float*)d_out + (size_t)BB * CC;  // [1000,5,2048]

    // ---- workspace layout ----
    char* w = (char*)d_ws;
    u16* Wgt     = (u16*)w;        w += (size_t)DD * NN * DD * 2;   // 40MB [2048][10240]
    u16* Wt      = (u16*)w;        w += (size_t)1024 * 2048 * 2 + 256; // 4MB shared W1t/W2t/Wct(padded rows)
    u16* ax      = (u16*)w;        w += (size_t)BB * NN * DD * 2;   // 5MB (reused as nodes)
    u16* nodes   = ax;
    u16* ah      = (u16*)w;        w += (size_t)BB * NN * HH * 2;   // 2.5MB
    // contiguous f32 partial buffers (single memset)
    float* g1_f32   = (float*)w;   w += (size_t)BB * NN * HH * 4;   // 5MB [1280][1024]
    float* g_f32    = (float*)w;   w += (size_t)BB * DD * 4;        // 2MB
    float* pred_f32 = (float*)w;   w += (size_t)BB * CC * 4;        // ~1MB
    char*  zero_end = w;
    u16* g_bf16  = (u16*)w;        w += (size_t)BB * DD * 2;        // 1MB
    int* cnt     = (int*)w;        w += 1024 * 4;
    int* start   = (int*)w;        w += 1024 * 4;
    int* order   = (int*)w;        w += 256 * 4;
    float* coef  = (float*)w;      w += 256 * 4;
    float* decayc= (float*)w;      w += 1024 * 4;

    // one memset for all f32 partial buffers
    hipMemsetAsync(g1_f32, 0, (size_t)(zero_end - (char*)g1_f32), stream);

    // ---- GCN path (bf16 MFMA, global_load_lds GEMMs) ----
    transpose_bf16<<<dim3(DD / 64, HH / 64), 256, 0, stream>>>(W1, Wt, DD, HH);
    adj_mix<false, false><<<(BB * DD / 4) / 256, 256, 0, stream>>>(adj, x, ax, DD);
    // G1: g1_f32 += ax @ W1   [1280,1024], split-K=2, grid 16x10x2=320
    gemm_gl<128, 64, true, false><<<dim3(HH / 64, (BB * NN) / 128, 2), 256, 0, stream>>>(
        ax, Wt, g1_f32, BB * NN, HH, DD, DD / 2);
    // ah = adj (x) relu(g1_f32)   (fused relu + bf16)
    adj_mix<false, true><<<(BB * HH / 4) / 256, 256, 0, stream>>>(adj, g1_f32, ah, HH);
    transpose_bf16<<<dim3(HH / 64, DD / 64), 256, 0, stream>>>(W2, Wt, HH, DD);
    // G2: nodes = ah @ W2   [1280,2048], grid 32x10=320, direct bf16
    gemm_gl<128, 64, false, false><<<dim3(DD / 64, (BB * NN) / 128, 1), 256, 0, stream>>>(
        ah, Wt, nodes, BB * NN, DD, HH, HH);
    transpose_bf16<<<dim3((NN * DD) / 64, DD / 64), 256, 0, stream>>>(Wg, Wgt, NN * DD, DD);
    // G3 (fc_g): split-K=16, grid 16x2x16=512
    gemm_gl<128, 128, true, false><<<dim3(DD / 128, BB / 128, 16), 256, 0, stream>>>(
        nodes, Wgt, g_f32, BB, DD, NN * DD, NN * DD / 16);
    finalize_g<<<(BB * DD / 4) / 256, 256, 0, stream>>>(g_f32, bg, g_bf16);
    transpose_bf16<<<dim3(DD / 64, 16), 256, 0, stream>>>(Wc, Wt, DD, CC);  // zero-padded to 1024 rows
    // G4 (fc_cls): split-K=8, grid 16x2x8=256
    gemm_gl<128, 64, true, false><<<dim3(16, BB / 128, 8), 256, 0, stream>>>(
        g_bf16, Wt, pred_f32, BB, CC, DD, DD / 8);
    finalize_pred<<<(BB * 250) / 256, 256, 0, stream>>>(pred_f32, bc, out_pred);

    // ---- prototype EMA + normalize (exact f32, fused) ----
    rank_build<<<1, 1024, 0, stream>>>(target, cnt, start, order, coef, decayc);
    proto_fused<<<CC * 2, 256, 0, stream>>>(prototypes, x, cnt, start, order,
                                            coef, decayc, out_protos);
}

// Round 5
// 309.773 us; speedup vs baseline: 1.1050x; 1.1050x over previous
//
#include <hip/hip_runtime.h>
#include <hip/hip_bf16.h>
#include <math.h>

#define BB 256
#define NN 5
#define DD 2048
#define CC 1000
#define HH 1024
#define PROTO_M 0.999f

typedef unsigned short u16;
typedef __attribute__((ext_vector_type(8))) short short8;   // 8 bf16
typedef __attribute__((ext_vector_type(4))) float f32x4;

__device__ __forceinline__ u16 f2bf(float f) {
    union { float f; unsigned u; } x; x.f = f;
    unsigned r = x.u + 0x7fff + ((x.u >> 16) & 1);   // RNE
    return (u16)(r >> 16);
}

// async global->LDS, 16B per lane; lds dest = wave-uniform base + lane*16
__device__ __forceinline__ void gload16(const u16* g, u16* l) {
    __builtin_amdgcn_global_load_lds(
        (const __attribute__((address_space(1))) unsigned int*)g,
        (__attribute__((address_space(3))) unsigned int*)l, 16, 0, 0);
}

// ---------------------------------------------------------------------------
// One 64x64 transpose tile: in f32 [K][N] -> out bf16 [N][K].
// OOB n rows (n >= N) are written as ZEROS (padded B operand for GEMM).
// ---------------------------------------------------------------------------
__device__ __forceinline__ void tr_tile(const float* __restrict__ in,
                                        u16* __restrict__ out,
                                        int K, int N, int k0, int n0) {
    constexpr int STR = 72;
    __shared__ u16 T[64 * STR];
    const int t = threadIdx.x;
    const int c4 = t % 16;
    const int rr = t / 16;
#pragma unroll
    for (int p = 0; p < 4; ++p) {
        int k = p * 16 + rr;
        int n = c4 * 4;
        if (n0 + n < N) {
            float4 v = *(const float4*)(in + (size_t)(k0 + k) * N + n0 + n);
            T[(n + 0) * STR + k] = f2bf(v.x);
            T[(n + 1) * STR + k] = f2bf(v.y);
            T[(n + 2) * STR + k] = f2bf(v.z);
            T[(n + 3) * STR + k] = f2bf(v.w);
        }
    }
    __syncthreads();
    const int ch = t % 8;
    const int nl0 = t / 8;
    const short8 zero8 = {0, 0, 0, 0, 0, 0, 0, 0};
#pragma unroll
    for (int q = 0; q < 2; ++q) {
        int nl = nl0 + q * 32;
        short8 v = zero8;
        if (n0 + nl < N) v = *(const short8*)(&T[nl * STR + ch * 8]);
        *(short8*)(out + (size_t)(n0 + nl) * K + k0 + ch * 8) = v;
    }
}

// W1 [2048,1024] -> W1t [1024][2048] : 32x16 = 512 tiles
// W2 [1024,2048] -> W2t [2048][1024] : 16x32 = 512 tiles
// Wc [2048,1000] -> Wct [1024pad][2048] : 32x16 = 512 tiles
__global__ __launch_bounds__(256) void transpose3(const float* __restrict__ W1,
                                                  const float* __restrict__ W2,
                                                  const float* __restrict__ Wc,
                                                  u16* __restrict__ W1t,
                                                  u16* __restrict__ W2t,
                                                  u16* __restrict__ Wct) {
    int bid = blockIdx.x;
    if (bid < 512) {
        tr_tile(W1, W1t, DD, HH, (bid % 32) * 64, (bid / 32) * 64);
    } else if (bid < 1024) {
        bid -= 512;
        tr_tile(W2, W2t, HH, DD, (bid % 16) * 64, (bid / 16) * 64);
    } else {
        bid -= 1024;
        tr_tile(Wc, Wct, DD, CC, (bid % 32) * 64, (bid / 32) * 64);
    }
}

// ---------------------------------------------------------------------------
// Wg_eff[o][d] = bf16( sum_n rn[n] * Wg[n*DD + d][o] ),  rn[n]=sum_m adj[n][m]
// out layout [2048 o][2048 d] (B^T for GEMM). 64x64 tiles, 1024 blocks.
// ---------------------------------------------------------------------------
__global__ __launch_bounds__(256) void build_wgeff(const float* __restrict__ Wg,
                                                   const float* __restrict__ adjp,
                                                   u16* __restrict__ out) {
    constexpr int STR = 72;
    __shared__ u16 T[64 * STR];
    float rn[NN];
#pragma unroll
    for (int n = 0; n < NN; ++n) {
        float s = 0.f;
#pragma unroll
        for (int m = 0; m < NN; ++m) s += adjp[n * NN + m];
        rn[n] = s;
    }
    const int o0 = blockIdx.x % 32 * 64;
    const int d0 = blockIdx.x / 32 * 64;
    const int t = threadIdx.x;
    const int c4 = t % 16;   // o-quad
    const int rr = t / 16;   // d-row
#pragma unroll
    for (int p = 0; p < 4; ++p) {
        int d = p * 16 + rr;
        int o = c4 * 4;
        float4 acc = {0.f, 0.f, 0.f, 0.f};
#pragma unroll
        for (int n = 0; n < NN; ++n) {
            float4 v = *(const float4*)(Wg + ((size_t)n * DD + d0 + d) * DD + o0 + o);
            acc.x += rn[n] * v.x; acc.y += rn[n] * v.y;
            acc.z += rn[n] * v.z; acc.w += rn[n] * v.w;
        }
        T[(o + 0) * STR + d] = f2bf(acc.x);
        T[(o + 1) * STR + d] = f2bf(acc.y);
        T[(o + 2) * STR + d] = f2bf(acc.z);
        T[(o + 3) * STR + d] = f2bf(acc.w);
    }
    __syncthreads();
    const int ch = t % 8;
    const int ol0 = t / 8;
#pragma unroll
    for (int q = 0; q < 2; ++q) {
        int ol = ol0 + q * 32;
        short8 v = *(const short8*)(&T[ol * STR + ch * 8]);
        *(short8*)(out + (size_t)(o0 + ol) * DD + d0 + ch * 8) = v;
    }
}

// ---------------------------------------------------------------------------
// colmix: s[b,d] = sum_m adj[0,m] * x[b,m,d]  -> bf16 [256][2048]
// ---------------------------------------------------------------------------
__global__ __launch_bounds__(256) void colmix(const float* __restrict__ adjp,
                                              const float* __restrict__ x,
                                              u16* __restrict__ s) {
    float av[NN];
#pragma unroll
    for (int m = 0; m < NN; ++m) av[m] = adjp[m];   // row 0
    int idx = blockIdx.x * blockDim.x + threadIdx.x;   // BB*DD/4 exact
    int b = idx / (DD / 4), d4 = idx % (DD / 4);
    float acc[4] = {0.f, 0.f, 0.f, 0.f};
#pragma unroll
    for (int m = 0; m < NN; ++m) {
        float4 v = *(const float4*)(x + ((size_t)b * NN + m) * DD + d4 * 4);
        acc[0] += av[m] * v.x; acc[1] += av[m] * v.y;
        acc[2] += av[m] * v.z; acc[3] += av[m] * v.w;
    }
    ushort4 o;
    o.x = f2bf(acc[0]); o.y = f2bf(acc[1]); o.z = f2bf(acc[2]); o.w = f2bf(acc[3]);
    *(ushort4*)(s + (size_t)b * DD + d4 * 4) = o;
}

// ---------------------------------------------------------------------------
// bf16 MFMA GEMM (global_load_lds staging, 64x64 tile, 4 waves 2x2):
// C[M,N] = A[M,K] @ Bt[N,K]^T (+bias) (+relu), direct store (bf16 or f32).
// Bt rows must be allocated/zero-padded to n0+64. K % 64 == 0, M % 64 == 0.
// ---------------------------------------------------------------------------
template<bool RELU, bool BIAS, bool OUTF32>
__global__ __launch_bounds__(256) void gemm_gl(const u16* __restrict__ A,
                                               const u16* __restrict__ Bt,
                                               const float* __restrict__ bias,
                                               void* __restrict__ C,
                                               int M, int N, int K) {
    constexpr int BM = 64, BN = 64;
    constexpr int FM = BM / 32, FN = BN / 32, SEG = BM / 32;
    __shared__ u16 As[BM * 64];
    __shared__ u16 Bs[BN * 64];
    const int t = threadIdx.x;
    const int lane = t & 63;
    const int w = t >> 6;
    const int wr = w >> 1, wc = w & 1;
    const int lr = lane & 15;
    const int kc = lane >> 4;
    const int lrow8 = lane >> 3;
    const int lc = lane & 7;
    const int m0 = blockIdx.y * BM;
    const int n0 = blockIdx.x * BN;

    f32x4 acc[FM][FN];
#pragma unroll
    for (int i = 0; i < FM; ++i)
#pragma unroll
        for (int j = 0; j < FN; ++j) acc[i][j] = (f32x4){0.f, 0.f, 0.f, 0.f};

    for (int k0 = 0; k0 < K; k0 += 64) {
        __syncthreads();
#pragma unroll
        for (int p = 0; p < SEG; ++p) {
            int s = p * 4 + w;
            int r = s * 8 + lrow8;
            int cs = lc ^ (r & 7);
            gload16(A + (size_t)(m0 + r) * K + k0 + cs * 8, &As[s * 512]);
        }
#pragma unroll
        for (int p = 0; p < SEG; ++p) {
            int s = p * 4 + w;
            int r = s * 8 + lrow8;
            int cs = lc ^ (r & 7);
            gload16(Bt + (size_t)(n0 + r) * K + k0 + cs * 8, &Bs[s * 512]);
        }
        __syncthreads();

#pragma unroll
        for (int ks = 0; ks < 2; ++ks) {
            short8 af[FM], bfr[FN];
#pragma unroll
            for (int i = 0; i < FM; ++i) {
                int row = wr * (BM / 2) + i * 16 + lr;
                int cs = (ks * 4 + kc) ^ (row & 7);
                af[i] = *(const short8*)(&As[row * 64 + cs * 8]);
            }
#pragma unroll
            for (int j = 0; j < FN; ++j) {
                int row = wc * (BN / 2) + j * 16 + lr;
                int cs = (ks * 4 + kc) ^ (row & 7);
                bfr[j] = *(const short8*)(&Bs[row * 64 + cs * 8]);
            }
#pragma unroll
            for (int i = 0; i < FM; ++i)
#pragma unroll
                for (int j = 0; j < FN; ++j)
                    acc[i][j] = __builtin_amdgcn_mfma_f32_16x16x32_bf16(
                        af[i], bfr[j], acc[i][j], 0, 0, 0);
        }
    }

    // epilogue: C/D layout col=lane&15, row=(lane>>4)*4+q
#pragma unroll
    for (int i = 0; i < FM; ++i) {
        int row = m0 + wr * (BM / 2) + i * 16 + kc * 4;
#pragma unroll
        for (int j = 0; j < FN; ++j) {
            int col = n0 + wc * (BN / 2) + j * 16 + lr;
            if (col >= N) continue;
            float bv = BIAS ? bias[col] : 0.f;
#pragma unroll
            for (int q = 0; q < 4; ++q) {
                float v = acc[i][j][q] + bv;
                if (RELU) v = fmaxf(v, 0.f);
                if (OUTF32) ((float*)C)[(size_t)(row + q) * N + col] = v;
                else        ((u16*)C)[(size_t)(row + q) * N + col] = f2bf(v);
            }
        }
    }
}

// ---------------------------------------------------------------------------
// Fused prototype EMA + L2 normalize (self-contained, closed-form scan):
// out[c] = normalize( protos[c]*M^k + sum_j 0.001*M^(k-1-j)*x[b_j] )
// where b_0<..<b_{k-1} are samples with target==c. Block = (c, half-of-D).
// ---------------------------------------------------------------------------
__global__ __launch_bounds__(256) void proto_fused(const float* __restrict__ protos,
                                                   const float* __restrict__ x,
                                                   const int* __restrict__ target,
                                                   float* __restrict__ out) {
    const int c = blockIdx.x >> 1;
    const int d = ((blockIdx.x & 1) * 256 + threadIdx.x) * 4;
    int k = 0;
    for (int b = 0; b < BB; ++b) k += (target[b] == c) ? 1 : 0;
    const float dec = powf(PROTO_M, (float)k);
    float4 v[NN];
#pragma unroll
    for (int n = 0; n < NN; ++n) {
        float4 p = *(const float4*)(protos + ((size_t)c * NN + n) * DD + d);
        v[n].x = p.x * dec; v[n].y = p.y * dec; v[n].z = p.z * dec; v[n].w = p.w * dec;
    }
    if (k > 0) {
        float p = (1.0f - PROTO_M) * powf(PROTO_M, (float)(k - 1));
        const float invm = 1.0f / PROTO_M;
        for (int b = 0; b < BB; ++b) {
            if (target[b] == c) {
#pragma unroll
                for (int n = 0; n < NN; ++n) {
                    float4 xv = *(const float4*)(x + ((size_t)b * NN + n) * DD + d);
                    v[n].x += p * xv.x; v[n].y += p * xv.y;
                    v[n].z += p * xv.z; v[n].w += p * xv.w;
                }
                p *= invm;
            }
        }
    }
    float ss[4] = {0.f, 0.f, 0.f, 0.f};
#pragma unroll
    for (int n = 0; n < NN; ++n) {
        ss[0] += v[n].x * v[n].x; ss[1] += v[n].y * v[n].y;
        ss[2] += v[n].z * v[n].z; ss[3] += v[n].w * v[n].w;
    }
    float inv[4];
#pragma unroll
    for (int j = 0; j < 4; ++j) inv[j] = 1.0f / fmaxf(sqrtf(ss[j]), 1e-12f);
#pragma unroll
    for (int n = 0; n < NN; ++n) {
        float4 o;
        o.x = v[n].x * inv[0]; o.y = v[n].y * inv[1];
        o.z = v[n].z * inv[2]; o.w = v[n].w * inv[3];
        *(float4*)(out + ((size_t)c * NN + n) * DD + d) = o;
    }
}

// ---------------------------------------------------------------------------
extern "C" void kernel_launch(void* const* d_in, const int* in_sizes, int n_in,
                              void* d_out, int out_size, void* d_ws, size_t ws_size,
                              hipStream_t stream) {
    const float* x          = (const float*)d_in[0];
    const int*   target     = (const int*)d_in[1];
    const float* prototypes = (const float*)d_in[2];
    const float* adj        = (const float*)d_in[3];
    const float* W1         = (const float*)d_in[4];
    const float* W2         = (const float*)d_in[5];
    const float* Wg         = (const float*)d_in[6];
    const float* bg         = (const float*)d_in[7];
    const float* Wc         = (const float*)d_in[8];
    const float* bc         = (const float*)d_in[9];

    float* out_pred   = (float*)d_out;                    // [256,1000]
    float* out_protos = (float*)d_out + (size_t)BB * CC;  // [1000,5,2048]

    // ---- workspace layout (all 16B-aligned) ----
    char* w = (char*)d_ws;
    u16* W1t   = (u16*)w;   w += (size_t)HH * DD * 2;        // 4MB [1024][2048]
    u16* W2t   = (u16*)w;   w += (size_t)DD * HH * 2;        // 4MB [2048][1024]
    u16* Wct   = (u16*)w;   w += (size_t)1024 * DD * 2;      // 4MB [1024pad][2048]
    u16* Wgte  = (u16*)w;   w += (size_t)DD * DD * 2;        // 8MB [2048][2048]
    u16* s     = (u16*)w;   w += (size_t)BB * DD * 2;        // 1MB
    u16* tb    = (u16*)w;   w += (size_t)BB * HH * 2;        // 0.5MB
    u16* u     = (u16*)w;   w += (size_t)BB * DD * 2;        // 1MB
    u16* g     = (u16*)w;   w += (size_t)BB * DD * 2;        // 1MB

    // weight prep (independent of activations)
    transpose3<<<1536, 256, 0, stream>>>(W1, W2, Wc, W1t, W2t, Wct);
    build_wgeff<<<1024, 256, 0, stream>>>(Wg, adj, Wgte);
    // s = row0(adj)-weighted node sum of x  (rank-1 adj collapse)
    colmix<<<(BB * DD / 4) / 256, 256, 0, stream>>>(adj, x, s);
    // t = relu(s @ W1)        [256,1024]
    gemm_gl<true, false, false><<<dim3(HH / 64, BB / 64), 256, 0, stream>>>(
        s, W1t, nullptr, tb, BB, HH, DD);
    // u = t @ W2              [256,2048]
    gemm_gl<false, false, false><<<dim3(DD / 64, BB / 64), 256, 0, stream>>>(
        tb, W2t, nullptr, u, BB, DD, HH);
    // g = u @ Wg_eff + bg     [256,2048]
    gemm_gl<false, true, false><<<dim3(DD / 64, BB / 64), 256, 0, stream>>>(
        u, Wgte, bg, g, BB, DD, DD);
    // pred = g @ Wc + bc      [256,1000] f32 -> d_out
    gemm_gl<false, true, true><<<dim3(1024 / 64, BB / 64), 256, 0, stream>>>(
        g, Wct, bc, out_pred, BB, CC, DD);
    // prototype EMA + normalize (exact f32)
    proto_fused<<<CC * 2, 256, 0, stream>>>(prototypes, x, target, out_protos);
}

// Round 6
// 302.283 us; speedup vs baseline: 1.1324x; 1.0248x over previous
//
#include <hip/hip_runtime.h>
#include <hip/hip_bf16.h>
#include <math.h>

#define BB 256
#define NN 5
#define DD 2048
#define CC 1000
#define HH 1024
#define PROTO_M 0.999f

typedef unsigned short u16;
typedef __attribute__((ext_vector_type(8))) short short8;   // 8 bf16
typedef __attribute__((ext_vector_type(4))) float f32x4;

__device__ __forceinline__ u16 f2bf(float f) {
    union { float f; unsigned u; } x; x.f = f;
    unsigned r = x.u + 0x7fff + ((x.u >> 16) & 1);   // RNE
    return (u16)(r >> 16);
}

// ---------------------------------------------------------------------------
// One 64x64 transpose tile: in f32 [K][N] -> out bf16 [N][K].
// OOB n rows (n >= N) are written as ZEROS (padded B operand for GEMM).
// T is the caller's 64*72 u16 LDS buffer.
// ---------------------------------------------------------------------------
__device__ __forceinline__ void tr_tile(const float* __restrict__ in,
                                        u16* __restrict__ out, u16* T,
                                        int K, int N, int k0, int n0) {
    constexpr int STR = 72;
    const int t = threadIdx.x;
    const int c4 = t % 16;
    const int rr = t / 16;
#pragma unroll
    for (int p = 0; p < 4; ++p) {
        int k = p * 16 + rr;
        int n = c4 * 4;
        if (n0 + n < N) {
            float4 v = *(const float4*)(in + (size_t)(k0 + k) * N + n0 + n);
            T[(n + 0) * STR + k] = f2bf(v.x);
            T[(n + 1) * STR + k] = f2bf(v.y);
            T[(n + 2) * STR + k] = f2bf(v.z);
            T[(n + 3) * STR + k] = f2bf(v.w);
        }
    }
    __syncthreads();
    const int ch = t % 8;
    const int nl0 = t / 8;
    const short8 zero8 = {0, 0, 0, 0, 0, 0, 0, 0};
#pragma unroll
    for (int q = 0; q < 2; ++q) {
        int nl = nl0 + q * 32;
        short8 v = zero8;
        if (n0 + nl < N) v = *(const short8*)(&T[nl * STR + ch * 8]);
        *(short8*)(out + (size_t)(n0 + nl) * K + k0 + ch * 8) = v;
    }
}

// ---------------------------------------------------------------------------
// Merged prep: W1t/W2t/Wct transposes, Wg_eff reduce+transpose, colmix s.
// blocks: [0,512) W1, [512,1024) W2, [1024,1536) Wc,
//         [1536,2560) Wg_eff, [2560,3072) colmix
// ---------------------------------------------------------------------------
__global__ __launch_bounds__(256) void prep_all(const float* __restrict__ W1,
                                                const float* __restrict__ W2,
                                                const float* __restrict__ Wc,
                                                const float* __restrict__ Wg,
                                                const float* __restrict__ adjp,
                                                const float* __restrict__ x,
                                                u16* __restrict__ W1t,
                                                u16* __restrict__ W2t,
                                                u16* __restrict__ Wct,
                                                u16* __restrict__ Wgte,
                                                u16* __restrict__ s) {
    constexpr int STR = 72;
    __shared__ u16 T[64 * STR];
    int bid = blockIdx.x;
    if (bid < 512) {
        tr_tile(W1, W1t, T, DD, HH, (bid % 32) * 64, (bid / 32) * 64);
    } else if (bid < 1024) {
        bid -= 512;
        tr_tile(W2, W2t, T, HH, DD, (bid % 16) * 64, (bid / 16) * 64);
    } else if (bid < 1536) {
        bid -= 1024;
        tr_tile(Wc, Wct, T, DD, CC, (bid % 32) * 64, (bid / 32) * 64);
    } else if (bid < 2560) {
        bid -= 1536;
        // Wg_eff[o][d] = bf16( sum_n rn[n] * Wg[n*DD+d][o] )
        float rn[NN];
#pragma unroll
        for (int n = 0; n < NN; ++n) {
            float ss = 0.f;
#pragma unroll
            for (int m = 0; m < NN; ++m) ss += adjp[n * NN + m];
            rn[n] = ss;
        }
        const int o0 = bid % 32 * 64;
        const int d0 = bid / 32 * 64;
        const int t = threadIdx.x;
        const int c4 = t % 16;
        const int rr = t / 16;
#pragma unroll
        for (int p = 0; p < 4; ++p) {
            int d = p * 16 + rr;
            int o = c4 * 4;
            float4 acc = {0.f, 0.f, 0.f, 0.f};
#pragma unroll
            for (int n = 0; n < NN; ++n) {
                float4 v = *(const float4*)(Wg + ((size_t)n * DD + d0 + d) * DD + o0 + o);
                acc.x += rn[n] * v.x; acc.y += rn[n] * v.y;
                acc.z += rn[n] * v.z; acc.w += rn[n] * v.w;
            }
            T[(o + 0) * STR + d] = f2bf(acc.x);
            T[(o + 1) * STR + d] = f2bf(acc.y);
            T[(o + 2) * STR + d] = f2bf(acc.z);
            T[(o + 3) * STR + d] = f2bf(acc.w);
        }
        __syncthreads();
        const int ch = t % 8;
        const int ol0 = t / 8;
#pragma unroll
        for (int q = 0; q < 2; ++q) {
            int ol = ol0 + q * 32;
            short8 v = *(const short8*)(&T[ol * STR + ch * 8]);
            *(short8*)(Wgte + (size_t)(o0 + ol) * DD + d0 + ch * 8) = v;
        }
    } else {
        bid -= 2560;
        // colmix: s[b,d] = sum_m adj[0,m] * x[b,m,d]
        float av[NN];
#pragma unroll
        for (int m = 0; m < NN; ++m) av[m] = adjp[m];
        int idx = bid * 256 + threadIdx.x;        // BB*DD/4 total
        int b = idx / (DD / 4), d4 = idx % (DD / 4);
        float acc[4] = {0.f, 0.f, 0.f, 0.f};
#pragma unroll
        for (int m = 0; m < NN; ++m) {
            float4 v = *(const float4*)(x + ((size_t)b * NN + m) * DD + d4 * 4);
            acc[0] += av[m] * v.x; acc[1] += av[m] * v.y;
            acc[2] += av[m] * v.z; acc[3] += av[m] * v.w;
        }
        ushort4 o;
        o.x = f2bf(acc[0]); o.y = f2bf(acc[1]);
        o.z = f2bf(acc[2]); o.w = f2bf(acc[3]);
        *(ushort4*)(s + (size_t)b * DD + d4 * 4) = o;
    }
}

// ---------------------------------------------------------------------------
// Barrier-free direct-fragment MFMA GEMM. 1 wave/block, 32x32 out per wave.
// Each lane loads its 16x16x32 fragments straight from global (L2-resident):
//   A-frag  = A [m0+i*16+lr][k + kc*8 .. +7]   (short8)
//   B-frag  = Bt[n0+j*16+lr][k + kc*8 .. +7]
// K compile-time -> full address folding + deep unroll pipelining. No LDS.
// Bt rows must be zero-padded to n0+32. C store guarded on col<N.
// ---------------------------------------------------------------------------
template<int K, bool RELU, bool BIAS, bool OUTF32>
__global__ __launch_bounds__(64) void gemm_direct(const u16* __restrict__ A,
                                                  const u16* __restrict__ Bt,
                                                  const float* __restrict__ bias,
                                                  void* __restrict__ C, int N) {
    const int lane = threadIdx.x;
    const int lr = lane & 15, kc = lane >> 4;
    const int m0 = blockIdx.y * 32, n0 = blockIdx.x * 32;
    const u16* pa0 = A + (size_t)(m0 + lr) * K + kc * 8;
    const u16* pa1 = pa0 + (size_t)16 * K;
    const u16* pb0 = Bt + (size_t)(n0 + lr) * K + kc * 8;
    const u16* pb1 = pb0 + (size_t)16 * K;

    f32x4 acc00 = {0.f, 0.f, 0.f, 0.f}, acc01 = acc00;
    f32x4 acc10 = acc00, acc11 = acc00;

    constexpr int NT = K / 32;
#pragma unroll 8
    for (int t = 0; t < NT; ++t) {
        short8 a0 = *(const short8*)(pa0 + t * 32);
        short8 a1 = *(const short8*)(pa1 + t * 32);
        short8 b0 = *(const short8*)(pb0 + t * 32);
        short8 b1 = *(const short8*)(pb1 + t * 32);
        acc00 = __builtin_amdgcn_mfma_f32_16x16x32_bf16(a0, b0, acc00, 0, 0, 0);
        acc01 = __builtin_amdgcn_mfma_f32_16x16x32_bf16(a0, b1, acc01, 0, 0, 0);
        acc10 = __builtin_amdgcn_mfma_f32_16x16x32_bf16(a1, b0, acc10, 0, 0, 0);
        acc11 = __builtin_amdgcn_mfma_f32_16x16x32_bf16(a1, b1, acc11, 0, 0, 0);
    }

    // epilogue: C/D layout col=lane&15, row=(lane>>4)*4+q
    f32x4 accs[2][2] = {{acc00, acc01}, {acc10, acc11}};
#pragma unroll
    for (int i = 0; i < 2; ++i) {
        int row = m0 + i * 16 + kc * 4;
#pragma unroll
        for (int j = 0; j < 2; ++j) {
            int col = n0 + j * 16 + lr;
            if (col >= N) continue;
            float bv = BIAS ? bias[col] : 0.f;
#pragma unroll
            for (int q = 0; q < 4; ++q) {
                float v = accs[i][j][q] + bv;
                if (RELU) v = fmaxf(v, 0.f);
                if (OUTF32) ((float*)C)[(size_t)(row + q) * N + col] = v;
                else        ((u16*)C)[(size_t)(row + q) * N + col] = f2bf(v);
            }
        }
    }
}

// ---------------------------------------------------------------------------
// Fused prototype EMA + L2 normalize (closed-form sequential scan):
// out[c] = normalize( protos[c]*M^k + sum_j 0.001*M^(k-1-j)*x[b_j] )
// where b_0<..<b_{k-1} are samples with target==c. Block = (c, half-of-D).
// ---------------------------------------------------------------------------
__global__ __launch_bounds__(256) void proto_fused(const float* __restrict__ protos,
                                                   const float* __restrict__ x,
                                                   const int* __restrict__ target,
                                                   float* __restrict__ out) {
    const int c = blockIdx.x >> 1;
    const int d = ((blockIdx.x & 1) * 256 + threadIdx.x) * 4;
    int k = 0;
    for (int b = 0; b < BB; ++b) k += (target[b] == c) ? 1 : 0;
    const float dec = powf(PROTO_M, (float)k);
    float4 v[NN];
#pragma unroll
    for (int n = 0; n < NN; ++n) {
        float4 p = *(const float4*)(protos + ((size_t)c * NN + n) * DD + d);
        v[n].x = p.x * dec; v[n].y = p.y * dec; v[n].z = p.z * dec; v[n].w = p.w * dec;
    }
    if (k > 0) {
        float p = (1.0f - PROTO_M) * powf(PROTO_M, (float)(k - 1));
        const float invm = 1.0f / PROTO_M;
        for (int b = 0; b < BB; ++b) {
            if (target[b] == c) {
#pragma unroll
                for (int n = 0; n < NN; ++n) {
                    float4 xv = *(const float4*)(x + ((size_t)b * NN + n) * DD + d);
                    v[n].x += p * xv.x; v[n].y += p * xv.y;
                    v[n].z += p * xv.z; v[n].w += p * xv.w;
                }
                p *= invm;
            }
        }
    }
    float ss[4] = {0.f, 0.f, 0.f, 0.f};
#pragma unroll
    for (int n = 0; n < NN; ++n) {
        ss[0] += v[n].x * v[n].x; ss[1] += v[n].y * v[n].y;
        ss[2] += v[n].z * v[n].z; ss[3] += v[n].w * v[n].w;
    }
    float inv[4];
#pragma unroll
    for (int j = 0; j < 4; ++j) inv[j] = 1.0f / fmaxf(sqrtf(ss[j]), 1e-12f);
#pragma unroll
    for (int n = 0; n < NN; ++n) {
        float4 o;
        o.x = v[n].x * inv[0]; o.y = v[n].y * inv[1];
        o.z = v[n].z * inv[2]; o.w = v[n].w * inv[3];
        *(float4*)(out + ((size_t)c * NN + n) * DD + d) = o;
    }
}

// ---------------------------------------------------------------------------
extern "C" void kernel_launch(void* const* d_in, const int* in_sizes, int n_in,
                              void* d_out, int out_size, void* d_ws, size_t ws_size,
                              hipStream_t stream) {
    const float* x          = (const float*)d_in[0];
    const int*   target     = (const int*)d_in[1];
    const float* prototypes = (const float*)d_in[2];
    const float* adj        = (const float*)d_in[3];
    const float* W1         = (const float*)d_in[4];
    const float* W2         = (const float*)d_in[5];
    const float* Wg         = (const float*)d_in[6];
    const float* bg         = (const float*)d_in[7];
    const float* Wc         = (const float*)d_in[8];
    const float* bc         = (const float*)d_in[9];

    float* out_pred   = (float*)d_out;                    // [256,1000]
    float* out_protos = (float*)d_out + (size_t)BB * CC;  // [1000,5,2048]

    // ---- workspace layout (16B-aligned) ----
    char* w = (char*)d_ws;
    u16* W1t  = (u16*)w;  w += (size_t)HH * DD * 2;      // 4MB  [1024][2048]
    u16* W2t  = (u16*)w;  w += (size_t)DD * HH * 2;      // 4MB  [2048][1024]
    u16* Wct  = (u16*)w;  w += (size_t)1024 * DD * 2;    // 4MB  [1024pad][2048]
    u16* Wgte = (u16*)w;  w += (size_t)DD * DD * 2;      // 8MB  [2048][2048]
    u16* s    = (u16*)w;  w += (size_t)BB * DD * 2;      // 1MB
    u16* tb   = (u16*)w;  w += (size_t)BB * HH * 2;      // 0.5MB
    u16* u    = (u16*)w;  w += (size_t)BB * DD * 2;      // 1MB
    u16* g    = (u16*)w;  w += (size_t)BB * DD * 2;      // 1MB

    // all weight prep + colmix in one dispatch (3072 blocks)
    prep_all<<<3072, 256, 0, stream>>>(W1, W2, Wc, Wg, adj, x,
                                       W1t, W2t, Wct, Wgte, s);
    // t = relu(s @ W1)      [256,1024]   256 blocks
    gemm_direct<DD, true, false, false><<<dim3(HH / 32, BB / 32), 64, 0, stream>>>(
        s, W1t, nullptr, tb, HH);
    // u = t @ W2            [256,2048]   512 blocks
    gemm_direct<HH, false, false, false><<<dim3(DD / 32, BB / 32), 64, 0, stream>>>(
        tb, W2t, nullptr, u, DD);
    // g = u @ Wg_eff + bg   [256,2048]   512 blocks
    gemm_direct<DD, false, true, false><<<dim3(DD / 32, BB / 32), 64, 0, stream>>>(
        u, Wgte, bg, g, DD);
    // pred = g @ Wc + bc    [256,1000] f32 -> d_out   256 blocks (N guard)
    gemm_direct<DD, false, true, true><<<dim3(1024 / 32, BB / 32), 64, 0, stream>>>(
        g, Wct, bc, out_pred, CC);
    // prototype EMA + normalize (exact f32)
    proto_fused<<<CC * 2, 256, 0, stream>>>(prototypes, x, target, out_protos);
}